// Round 4
// baseline (386.911 us; speedup 1.0000x reference)
//
#include <hip/hip_runtime.h>
#include <hip/hip_bf16.h>

// CSPN 3x3 propagation, float32 (verified PASS round 3, absmax 0.0625).
//
//   out[b,y,x] = sum_{t=0..8, t=dy*3+dx} k[b,t,y,x] * patch(t)
//   patch(t) = zero-padded input at (y+dy-1, x+dx-1), EXCEPT t==4 (center),
//   which is input0[b,y,x]. Taps 3/5 still read original input (round-1 bug).
//
// Memory-bound: compulsory traffic 329 MB (246.5 MB kernel stream-once +
// 27.4 MB input x3-reused + 27.4 MB input0 + 27.4 MB out) -> ~49 us at the
// 6.7 TB/s this device's fill kernels achieve. Round-4 changes:
//   - nontemporal loads for kernel tensor + input0 (zero reuse) and
//     nontemporal store for out: keep L2 free for the y-reused input rows.
//   - 8 px/thread (two aligned 16 B vectors per plane): half the index and
//     edge-handling arithmetic per byte moved.

#define BS 16
#define H  352
#define W  1216
#define HW (H * W)
#define WO (W / 8)   // 152

typedef float v4f __attribute__((ext_vector_type(4)));

__device__ __forceinline__ v4f ntload4(const float* p) {
    return __builtin_nontemporal_load((const v4f*)p);
}
__device__ __forceinline__ void ntstore4(float* p, v4f v) {
    __builtin_nontemporal_store(v, (v4f*)p);
}

__global__ __launch_bounds__(256) void cspn_kernel(
    const float* __restrict__ ker,   // [BS, 9, H, W]
    const float* __restrict__ inp,   // [BS, 1, H, W]
    const float* __restrict__ inp0,  // [BS, 1, H, W]
    float* __restrict__ out)         // [BS, 1, H, W]
{
    int tid = blockIdx.x * blockDim.x + threadIdx.x;
    const int total = BS * H * WO;
    if (tid >= total) return;

    int xo = tid % WO;
    int t  = tid / WO;
    int y  = t % H;
    int b  = t / H;
    int x0 = xo * 8;

    // Gather 3 input rows, 10 columns each: input[y+dy-1][x0-1 .. x0+8].
    // Cached loads: each row is read by 3 vertically-adjacent y's (L1/L2 hit).
    // NEVER overwritten — taps 3 and 5 need the original center row.
    float row[3][10];
    const float* inb = inp + (size_t)b * HW;
#pragma unroll
    for (int dy = 0; dy < 3; ++dy) {
        int yy = y + dy - 1;
        if (yy < 0 || yy >= H) {
#pragma unroll
            for (int c = 0; c < 10; ++c) row[dy][c] = 0.f;
        } else {
            const float* r = inb + (size_t)yy * W + x0;
            v4f a = *(const v4f*)r;
            v4f c = *(const v4f*)(r + 4);
            row[dy][1] = a.x; row[dy][2] = a.y; row[dy][3] = a.z; row[dy][4] = a.w;
            row[dy][5] = c.x; row[dy][6] = c.y; row[dy][7] = c.z; row[dy][8] = c.w;
            row[dy][0] = (x0 > 0)     ? r[-1] : 0.f;
            row[dy][9] = (x0 + 8 < W) ? r[8]  : 0.f;
        }
    }

    // Center tap values (tap 4 ONLY) come from input0. Stream-once -> nt.
    float cen[8];
    {
        const float* c0p = inp0 + (size_t)b * HW + (size_t)y * W + x0;
        v4f a = ntload4(c0p);
        v4f c = ntload4(c0p + 4);
        cen[0] = a.x; cen[1] = a.y; cen[2] = a.z; cen[3] = a.w;
        cen[4] = c.x; cen[5] = c.y; cen[6] = c.z; cen[7] = c.w;
    }

    float acc[8] = {0.f, 0.f, 0.f, 0.f, 0.f, 0.f, 0.f, 0.f};
    const float* kb = ker + (size_t)b * 9 * HW + (size_t)y * W + x0;
#pragma unroll
    for (int t9 = 0; t9 < 9; ++t9) {
        int dy = t9 / 3, dx = t9 % 3;
        const float* kp = kb + (size_t)t9 * HW;
        v4f k0 = ntload4(kp);        // kernel tensor: stream-once -> nt
        v4f k1 = ntload4(kp + 4);
        float kf[8] = {k0.x, k0.y, k0.z, k0.w, k1.x, k1.y, k1.z, k1.w};
#pragma unroll
        for (int l = 0; l < 8; ++l) {
            float p = (t9 == 4) ? cen[l] : row[dy][dx + l];
            acc[l] = fmaf(kf[l], p, acc[l]);
        }
    }

    float* op = out + (size_t)b * HW + (size_t)y * W + x0;
    v4f o0 = {acc[0], acc[1], acc[2], acc[3]};
    v4f o1 = {acc[4], acc[5], acc[6], acc[7]};
    ntstore4(op, o0);
    ntstore4(op + 4, o1);
}

extern "C" void kernel_launch(void* const* d_in, const int* in_sizes, int n_in,
                              void* d_out, int out_size, void* d_ws, size_t ws_size,
                              hipStream_t stream) {
    // Kernel tensor is the 9x-sized buffer; remaining two keep dict order:
    // input, then input0.
    int ki = 0;
    for (int i = 1; i < n_in; ++i)
        if (in_sizes[i] > in_sizes[ki]) ki = i;
    int rest[2], nr = 0;
    for (int i = 0; i < n_in; ++i)
        if (i != ki) rest[nr++] = i;

    const float* ker  = (const float*)d_in[ki];
    const float* inp  = (const float*)d_in[rest[0]];
    const float* inp0 = (const float*)d_in[rest[1]];
    float* out = (float*)d_out;

    const int total = BS * H * WO;           // threads, 8 px each
    const int block = 256;
    const int grid  = (total + block - 1) / block;
    cspn_kernel<<<grid, block, 0, stream>>>(ker, inp, inp0, out);
}

// Round 5
// 371.799 us; speedup vs baseline: 1.0406x; 1.0406x over previous
//
#include <hip/hip_runtime.h>
#include <hip/hip_bf16.h>

// CSPN 3x3 propagation, float32 (PASS round 3 @ absmax 0.0625).
//
//   out[b,y,x] = sum_{t=0..8, t=dy*3+dx} k[b,t,y,x] * patch(t)
//   patch(t) = zero-padded input at (y+dy-1, x+dx-1), EXCEPT t==4 (center),
//   which is input0[b,y,x]. Taps 3/5 read the ORIGINAL input row (round-1 bug:
//   never overwrite row[1] with input0).
//
// Round-5: revert round-4's nt hints + 8px/thread (regressed 367->387 us
// total; register pressure + lost L2 write-combining). Back to the known-good
// 4 px/thread float4 structure, plus ONE new change:
//
// XCD-contiguous block swizzle: default round-robin block->XCD mapping puts
// vertically-adjacent rows on different XCDs, so the 3x-reused input rows are
// HBM-fetched up to 3x (per-XCD L2s are not shared) — ~+55 MB on 329 MB
// compulsory. work = (bid%8)*(grid/8) + bid/8 gives each XCD a contiguous
// row range so vertical reuse hits its own L2. Perf heuristic only.

#define BS 16
#define H  352
#define W  1216
#define HW (H * W)
#define WQ (W / 4)   // 304
#define NXCD 8

__global__ __launch_bounds__(256) void cspn_kernel(
    const float* __restrict__ ker,   // [BS, 9, H, W]
    const float* __restrict__ inp,   // [BS, 1, H, W]
    const float* __restrict__ inp0,  // [BS, 1, H, W]
    float* __restrict__ out)         // [BS, 1, H, W]
{
    // Contiguous-per-XCD swizzle. grid = BS*H*WQ/256 = 6688, divisible by 8.
    int nblk  = gridDim.x;
    int chunk = nblk / NXCD;
    int bid   = blockIdx.x;
    int swz   = (bid % NXCD) * chunk + (bid / NXCD);
    int tid   = swz * blockDim.x + threadIdx.x;

    const int total = BS * H * WQ;
    if (tid >= total) return;

    int xq = tid % WQ;
    int t  = tid / WQ;
    int y  = t % H;
    int b  = t / H;
    int x0 = xq * 4;

    // Gather 3 input rows, 6 columns each: input[y+dy-1][x0-1 .. x0+4].
    // Cached loads: 3x vertical reuse should L2-hit within the XCD now.
    // NEVER overwritten — taps 3 and 5 need the original center row.
    float row[3][6];
    const float* inb = inp + (size_t)b * HW;
#pragma unroll
    for (int dy = 0; dy < 3; ++dy) {
        int yy = y + dy - 1;
        if (yy < 0 || yy >= H) {
#pragma unroll
            for (int c = 0; c < 6; ++c) row[dy][c] = 0.f;
        } else {
            const float* r = inb + (size_t)yy * W + x0;
            float4 v = *(const float4*)r;
            row[dy][1] = v.x; row[dy][2] = v.y;
            row[dy][3] = v.z; row[dy][4] = v.w;
            row[dy][0] = (x0 > 0)     ? r[-1] : 0.f;
            row[dy][5] = (x0 + 4 < W) ? r[4]  : 0.f;
        }
    }

    // Center tap values (tap 4 ONLY) come from input0.
    float4 c0 = *(const float4*)(inp0 + (size_t)b * HW + (size_t)y * W + x0);
    float cen[4] = {c0.x, c0.y, c0.z, c0.w};

    float acc[4] = {0.f, 0.f, 0.f, 0.f};
    const float* kb = ker + (size_t)b * 9 * HW + (size_t)y * W + x0;
#pragma unroll
    for (int t9 = 0; t9 < 9; ++t9) {
        int dy = t9 / 3, dx = t9 % 3;
        float4 kv = *(const float4*)(kb + (size_t)t9 * HW);
        float kf[4] = {kv.x, kv.y, kv.z, kv.w};
#pragma unroll
        for (int l = 0; l < 4; ++l) {
            float p = (t9 == 4) ? cen[l] : row[dy][dx + l];
            acc[l] = fmaf(kf[l], p, acc[l]);
        }
    }

    float4 o = make_float4(acc[0], acc[1], acc[2], acc[3]);
    *(float4*)(out + (size_t)b * HW + (size_t)y * W + x0) = o;
}

extern "C" void kernel_launch(void* const* d_in, const int* in_sizes, int n_in,
                              void* d_out, int out_size, void* d_ws, size_t ws_size,
                              hipStream_t stream) {
    // Kernel tensor is the 9x-sized buffer; remaining two keep dict order:
    // input, then input0.
    int ki = 0;
    for (int i = 1; i < n_in; ++i)
        if (in_sizes[i] > in_sizes[ki]) ki = i;
    int rest[2], nr = 0;
    for (int i = 0; i < n_in; ++i)
        if (i != ki) rest[nr++] = i;

    const float* ker  = (const float*)d_in[ki];
    const float* inp  = (const float*)d_in[rest[0]];
    const float* inp0 = (const float*)d_in[rest[1]];
    float* out = (float*)d_out;

    const int total = BS * H * WQ;           // threads, 4 px each
    const int block = 256;
    const int grid  = (total + block - 1) / block;   // 6688
    cspn_kernel<<<grid, block, 0, stream>>>(ker, inp, inp0, out);
}